// Round 1
// baseline (2360.771 us; speedup 1.0000x reference)
//
#include <hip/hip_runtime.h>
#include <hip/hip_bf16.h>
#include <math.h>

#define S_LEN 2048
#define DMODEL 512
#define NHEAD 8
#define HDIM 64
#define NLAYER 4

typedef __attribute__((ext_vector_type(4))) float float4v;
typedef __attribute__((ext_vector_type(4))) short short4v;
typedef __attribute__((ext_vector_type(8))) short short8v;
typedef __attribute__((ext_vector_type(8))) __bf16 bf16x8;

struct HalfPair { short4v lo, hi; };

__device__ __forceinline__ float4v mfma16x16x32(short8v a, short8v b, float4v c) {
    return __builtin_amdgcn_mfma_f32_16x16x32_bf16(
        __builtin_bit_cast(bf16x8, a), __builtin_bit_cast(bf16x8, b), c, 0, 0, 0);
}

__device__ __forceinline__ short f2bf(float f) {
    return __builtin_bit_cast(short, __float2bfloat16(f));
}

__device__ __forceinline__ float gelu_tanh(float x) {
    return 0.5f * x * (1.0f + tanhf(0.7978845608028654f * (x + 0.044715f * x * x * x)));
}

// x[s,:] = wte[id[s],:] + wpe[s,:]
__global__ __launch_bounds__(128) void embed_kernel(
        const int* __restrict__ ids, const float* __restrict__ wte,
        const float* __restrict__ wpe, float* __restrict__ x) {
    int s = blockIdx.x;
    int d4 = threadIdx.x;  // 128 threads * 4 floats = 512
    int id = ids[s];
    float4v a = *(const float4v*)(wte + (long)id * DMODEL + d4 * 4);
    float4v b = *(const float4v*)(wpe + (long)s * DMODEL + d4 * 4);
    *(float4v*)(x + (long)s * DMODEL + d4 * 4) = a + b;
}

// out_bf16[s,:] = LN(x[s,:]) * w + b   (one block per row, 256 thr, 2 elems each)
__global__ __launch_bounds__(256) void ln_kernel(
        const float* __restrict__ x, const float* __restrict__ w,
        const float* __restrict__ b, __hip_bfloat16* __restrict__ out) {
    int s = blockIdx.x, t = threadIdx.x;
    const float* row = x + (long)s * DMODEL;
    float v0 = row[2 * t], v1 = row[2 * t + 1];
    float sum = v0 + v1, sq = v0 * v0 + v1 * v1;
#pragma unroll
    for (int off = 32; off > 0; off >>= 1) {
        sum += __shfl_xor(sum, off);
        sq  += __shfl_xor(sq, off);
    }
    __shared__ float red[8];
    int lane = t & 63, wv = t >> 6;
    if (lane == 0) { red[wv] = sum; red[4 + wv] = sq; }
    __syncthreads();
    sum = red[0] + red[1] + red[2] + red[3];
    sq  = red[4] + red[5] + red[6] + red[7];
    float mu  = sum * (1.0f / DMODEL);
    float var = sq * (1.0f / DMODEL) - mu * mu;
    float rs  = rsqrtf(var + 1e-5f);
    float y0 = (v0 - mu) * rs * w[2 * t] + b[2 * t];
    float y1 = (v1 - mu) * rs * w[2 * t + 1] + b[2 * t + 1];
    unsigned int packed = (unsigned short)f2bf(y0) |
                          ((unsigned int)(unsigned short)f2bf(y1) << 16);
    ((unsigned int*)out)[(long)s * (DMODEL / 2) + t] = packed;
}

// C[M,N] = A_bf16[M,512] @ B_f32 (+bias, epilogue).  M=2048, K=512 fixed.
// BLAYOUT 0: B is [K,N] row-major (weights).  1: B is [N,K] row-major (head_w).
// EPI 0: Cf = acc + bias          (qkv buffer)
// EPI 1: Cf += acc + bias         (residual update of x)
// EPI 2: Cb = bf16(gelu(acc+bias))
// EPI 3: Cf = acc                 (logits, no bias)
template<int BLAYOUT, int EPI>
__global__ __launch_bounds__(256) void gemm_kernel(
        const short* __restrict__ A, const float* __restrict__ B,
        const float* __restrict__ bias, float* __restrict__ Cf,
        __hip_bfloat16* __restrict__ Cb, int N) {
    const int K = DMODEL;
    __shared__ __align__(16) short As[128 * 32];
    __shared__ __align__(16) short Bs[128 * 32];
    int t = threadIdx.x;
    int l = t & 63, wv = t >> 6;
    int wr = wv >> 1, wc = wv & 1;
    int m0 = blockIdx.y * 128, n0 = blockIdx.x * 128;
    int ln15 = l & 15, lh = l >> 4;

    float4v acc[4][4];
#pragma unroll
    for (int i = 0; i < 4; ++i)
#pragma unroll
        for (int j = 0; j < 4; ++j)
            acc[i][j] = (float4v){0.f, 0.f, 0.f, 0.f};

    int am = t >> 1;           // A stage: row
    int acb = (t & 1) * 2;     // A stage: first 16B chunk

    for (int k0 = 0; k0 < K; k0 += 32) {
        // ---- stage A (bf16, [128][32], XOR-swizzled 8B units) ----
        const short* Ag = A + (long)(m0 + am) * K + k0;
#pragma unroll
        for (int cc = 0; cc < 2; ++cc) {
            int c = acb + cc;
            float4v v = *(const float4v*)(Ag + c * 8);
            int cd = c ^ ((am >> 1) & 3);
            *(float4v*)(As + am * 32 + cd * 8) = v;
        }
        // ---- stage B (f32 -> bf16 convert in-reg) ----
        if constexpr (BLAYOUT == 0) {
            int n = t & 127;
            int kgb = t >> 7;
            const float* Bg = B + (long)k0 * N + n0 + n;
#pragma unroll
            for (int g = 0; g < 4; ++g) {
                int kg = kgb + g * 2;  // 0..7
                short4v sv;
#pragma unroll
                for (int jj = 0; jj < 4; ++jj)
                    sv[jj] = f2bf(Bg[(long)(kg * 4 + jj) * N]);
                int ud = kg ^ (n & 6);
                *(short4v*)(Bs + n * 32 + ud * 4) = sv;
            }
        } else {
            int n = t >> 1;
            int uh = (t & 1) * 4;
            const float* Bg = B + (long)(n0 + n) * K + k0;
#pragma unroll
            for (int uu = 0; uu < 4; ++uu) {
                int u = uh + uu;
                float4v v = *(const float4v*)(Bg + u * 4);
                short4v sv;
#pragma unroll
                for (int jj = 0; jj < 4; ++jj) sv[jj] = f2bf(v[jj]);
                int ud = u ^ (n & 6);
                *(short4v*)(Bs + n * 32 + ud * 4) = sv;
            }
        }
        __syncthreads();
        // ---- fragments + MFMA ----
        short8v af[4], bfr[4];
#pragma unroll
        for (int i = 0; i < 4; ++i) {
            int r = wr * 64 + i * 16 + ln15;
            HalfPair p{*(const short4v*)(As + r * 32 + ((lh ^ (r & 6)) << 2)),
                       *(const short4v*)(As + r * 32 + (((lh + 4) ^ (r & 6)) << 2))};
            af[i] = __builtin_bit_cast(short8v, p);
        }
#pragma unroll
        for (int j = 0; j < 4; ++j) {
            int r = wc * 64 + j * 16 + ln15;
            HalfPair p{*(const short4v*)(Bs + r * 32 + ((lh ^ (r & 6)) << 2)),
                       *(const short4v*)(Bs + r * 32 + (((lh + 4) ^ (r & 6)) << 2))};
            bfr[j] = __builtin_bit_cast(short8v, p);
        }
#pragma unroll
        for (int i = 0; i < 4; ++i)
#pragma unroll
            for (int j = 0; j < 4; ++j)
                acc[i][j] = mfma16x16x32(af[i], bfr[j], acc[i][j]);
        __syncthreads();
    }

    // ---- epilogue: D[row][col], row=(l>>4)*4+r, col=l&15 (m89-verified) ----
    int colb = n0 + wc * 64 + ln15;
    int rowb = m0 + wr * 64 + (lh << 2);
#pragma unroll
    for (int i = 0; i < 4; ++i) {
#pragma unroll
        for (int j = 0; j < 4; ++j) {
            int col = colb + j * 16;
#pragma unroll
            for (int r = 0; r < 4; ++r) {
                int row = rowb + i * 16 + r;
                long idx = (long)row * N + col;
                float v = acc[i][j][r];
                if constexpr (EPI == 0) Cf[idx] = v + bias[col];
                else if constexpr (EPI == 1) Cf[idx] += v + bias[col];
                else if constexpr (EPI == 2)
                    Cb[idx] = __float2bfloat16(gelu_tanh(v + bias[col]));
                else Cf[idx] = v;
            }
        }
    }
}

// SIMT f32 flash attention. Block = 4 q-rows (1 wave each) of one head.
// qkv [S][1536]: q at col h*64+d, k at 512+..., v at 1024+...
__global__ __launch_bounds__(256) void attn_kernel(
        const float* __restrict__ qkv, __hip_bfloat16* __restrict__ O) {
    __shared__ __align__(16) float Kc[64 * 64];
    __shared__ __align__(16) float Vc[64 * 64];
    __shared__ __align__(16) float qs[4 * 64];
    __shared__ float ps[4 * 64];
    int t = threadIdx.x, l = t & 63, wv = t >> 6;
    int hh = blockIdx.y;
    int qr = blockIdx.x * 4 + wv;
    qs[wv * 64 + l] = qkv[(long)qr * 1536 + hh * 64 + l];
    float m_run = -1e30f, l_run = 0.f, o = 0.f;
    int nch = ((blockIdx.x * 4 + 3) >> 6) + 1;
    int sj = t >> 2, sp = t & 3;
    for (int c = 0; c < nch; ++c) {
        int kk0 = c << 6;
        const float* kp = qkv + (long)(kk0 + sj) * 1536 + 512 + hh * 64 + sp * 16;
#pragma unroll
        for (int i = 0; i < 4; ++i) {
            float4v kvv = *(const float4v*)(kp + i * 4);
            float4v vvv = *(const float4v*)(kp + 512 + i * 4);
            int u = sp * 4 + i;
            int us = u ^ (sj & 15);  // swizzle so reads are ~conflict-free
            *(float4v*)(Kc + sj * 64 + us * 4) = kvv;
            *(float4v*)(Vc + sj * 64 + us * 4) = vvv;
        }
        __syncthreads();
        if (kk0 <= qr) {
            // scores: lane = key index
            float s = 0.f;
#pragma unroll
            for (int u = 0; u < 16; ++u) {
                float4v kv = *(const float4v*)(Kc + l * 64 + ((u ^ (l & 15)) << 2));
                float4v qv = *(const float4v*)(qs + wv * 64 + u * 4);
                s += kv[0] * qv[0] + kv[1] * qv[1] + kv[2] * qv[2] + kv[3] * qv[3];
            }
            s *= 0.125f;  // 1/sqrt(64)
            if (kk0 + l > qr) s = -3.0e38f;  // causal mask
            float mx = s;
#pragma unroll
            for (int off = 32; off > 0; off >>= 1) mx = fmaxf(mx, __shfl_xor(mx, off));
            mx = fmaxf(mx, m_run);
            float p = __expf(s - mx);
            float psum = p;
#pragma unroll
            for (int off = 32; off > 0; off >>= 1) psum += __shfl_xor(psum, off);
            float scale = __expf(m_run - mx);
            l_run = l_run * scale + psum;
            m_run = mx;
            ps[wv * 64 + l] = p;
            o *= scale;
            // PV: lane = d
            int du = l >> 2, dr = l & 3;
#pragma unroll 8
            for (int j2 = 0; j2 < 64; ++j2) {
                o = fmaf(ps[wv * 64 + j2],
                         Vc[j2 * 64 + ((du ^ (j2 & 15)) << 2) + dr], o);
            }
        }
        __syncthreads();
    }
    O[(long)qr * 512 + hh * 64 + l] = __float2bfloat16(o / l_run);
}

extern "C" void kernel_launch(void* const* d_in, const int* in_sizes, int n_in,
                              void* d_out, int out_size, void* d_ws, size_t ws_size,
                              hipStream_t stream) {
    const int*   ids  = (const int*)d_in[0];
    const float* wte  = (const float*)d_in[1];
    const float* wpe  = (const float*)d_in[2];
    const float* qkvw = (const float*)d_in[3];
    const float* qkvb = (const float*)d_in[4];
    const float* pw   = (const float*)d_in[5];
    const float* pb   = (const float*)d_in[6];
    const float* l1w  = (const float*)d_in[7];
    const float* l1b  = (const float*)d_in[8];
    const float* l2w  = (const float*)d_in[9];
    const float* l2b  = (const float*)d_in[10];
    const float* fw   = (const float*)d_in[11];
    const float* fb   = (const float*)d_in[12];
    const float* mw   = (const float*)d_in[13];
    const float* mb   = (const float*)d_in[14];
    const float* lfw  = (const float*)d_in[15];
    const float* lfb  = (const float*)d_in[16];
    const float* hw   = (const float*)d_in[17];

    // workspace: x f32 (4MB) | qkv f32 (12MB) | h bf16 (2MB) | o bf16 (2MB) | g bf16 (2MB)
    float* x   = (float*)d_ws;
    float* qkv = x + (long)S_LEN * DMODEL;
    short* h   = (short*)(qkv + (long)S_LEN * 3 * DMODEL);
    short* o   = h + (long)S_LEN * DMODEL;
    short* g   = o + (long)S_LEN * DMODEL;
    float* out = (float*)d_out;

    embed_kernel<<<S_LEN, 128, 0, stream>>>(ids, wte, wpe, x);
    for (int lyr = 0; lyr < NLAYER; ++lyr) {
        ln_kernel<<<S_LEN, 256, 0, stream>>>(x, l1w + lyr * DMODEL, l1b + lyr * DMODEL,
                                             (__hip_bfloat16*)h);
        gemm_kernel<0, 0><<<dim3(12, 16), 256, 0, stream>>>(
            h, qkvw + (long)lyr * DMODEL * 1536, qkvb + lyr * 1536, qkv, nullptr, 1536);
        attn_kernel<<<dim3(512, 8), 256, 0, stream>>>(qkv, (__hip_bfloat16*)o);
        gemm_kernel<0, 1><<<dim3(4, 16), 256, 0, stream>>>(
            o, pw + (long)lyr * DMODEL * DMODEL, pb + lyr * DMODEL, x, nullptr, DMODEL);
        ln_kernel<<<S_LEN, 256, 0, stream>>>(x, l2w + lyr * DMODEL, l2b + lyr * DMODEL,
                                             (__hip_bfloat16*)h);
        gemm_kernel<0, 2><<<dim3(4, 16), 256, 0, stream>>>(
            h, fw + (long)lyr * DMODEL * DMODEL, fb + lyr * DMODEL, nullptr,
            (__hip_bfloat16*)g, DMODEL);
        gemm_kernel<0, 1><<<dim3(4, 16), 256, 0, stream>>>(
            g, mw + (long)lyr * DMODEL * DMODEL, mb + lyr * DMODEL, x, nullptr, DMODEL);
    }
    ln_kernel<<<S_LEN, 256, 0, stream>>>(x, lfw, lfb, (__hip_bfloat16*)h);
    gemm_kernel<1, 3><<<dim3(250, 16), 256, 0, stream>>>(h, hw, nullptr, out, nullptr, 32000);
}

// Round 2
// 1232.045 us; speedup vs baseline: 1.9161x; 1.9161x over previous
//
#include <hip/hip_runtime.h>
#include <hip/hip_bf16.h>
#include <math.h>

#define S_LEN 2048
#define DMODEL 512
#define NHEAD 8
#define HDIM 64
#define NLAYER 4

typedef __attribute__((ext_vector_type(4))) float float4v;
typedef __attribute__((ext_vector_type(4))) short short4v;
typedef __attribute__((ext_vector_type(8))) short short8v;
typedef __attribute__((ext_vector_type(8))) __bf16 bf16x8;

struct HalfPair { short4v lo, hi; };

__device__ __forceinline__ float4v mfma16x16x32(short8v a, short8v b, float4v c) {
    return __builtin_amdgcn_mfma_f32_16x16x32_bf16(
        __builtin_bit_cast(bf16x8, a), __builtin_bit_cast(bf16x8, b), c, 0, 0, 0);
}

__device__ __forceinline__ short f2bf(float f) {
    return __builtin_bit_cast(short, __float2bfloat16(f));
}

__device__ __forceinline__ float gelu_tanh(float x) {
    return 0.5f * x * (1.0f + tanhf(0.7978845608028654f * (x + 0.044715f * x * x * x)));
}

// x[s,:] = wte[id[s],:] + wpe[s,:]
__global__ __launch_bounds__(128) void embed_kernel(
        const int* __restrict__ ids, const float* __restrict__ wte,
        const float* __restrict__ wpe, float* __restrict__ x) {
    int s = blockIdx.x;
    int d4 = threadIdx.x;
    int id = ids[s];
    float4v a = *(const float4v*)(wte + (long)id * DMODEL + d4 * 4);
    float4v b = *(const float4v*)(wpe + (long)s * DMODEL + d4 * 4);
    *(float4v*)(x + (long)s * DMODEL + d4 * 4) = a + b;
}

// f32 -> bf16 bulk convert (8 elems/thread)
__global__ __launch_bounds__(256) void f2bf_kernel(
        const float* __restrict__ in, short* __restrict__ out, long n) {
    long i = ((long)blockIdx.x * 256 + threadIdx.x) * 8;
    if (i >= n) return;
    float4v a = *(const float4v*)(in + i);
    float4v b = *(const float4v*)(in + i + 4);
    short8v s;
#pragma unroll
    for (int j = 0; j < 4; ++j) { s[j] = f2bf(a[j]); s[4 + j] = f2bf(b[j]); }
    *(short8v*)(out + i) = s;
}

// out_bf16[s,:] = LN(x[s,:]) * w + b
__global__ __launch_bounds__(256) void ln_kernel(
        const float* __restrict__ x, const float* __restrict__ w,
        const float* __restrict__ b, __hip_bfloat16* __restrict__ out) {
    int s = blockIdx.x, t = threadIdx.x;
    const float* row = x + (long)s * DMODEL;
    float v0 = row[2 * t], v1 = row[2 * t + 1];
    float sum = v0 + v1, sq = v0 * v0 + v1 * v1;
#pragma unroll
    for (int off = 32; off > 0; off >>= 1) {
        sum += __shfl_xor(sum, off);
        sq  += __shfl_xor(sq, off);
    }
    __shared__ float red[8];
    int lane = t & 63, wv = t >> 6;
    if (lane == 0) { red[wv] = sum; red[4 + wv] = sq; }
    __syncthreads();
    sum = red[0] + red[1] + red[2] + red[3];
    sq  = red[4] + red[5] + red[6] + red[7];
    float mu  = sum * (1.0f / DMODEL);
    float var = sq * (1.0f / DMODEL) - mu * mu;
    float rs  = rsqrtf(var + 1e-5f);
    float y0 = (v0 - mu) * rs * w[2 * t] + b[2 * t];
    float y1 = (v1 - mu) * rs * w[2 * t + 1] + b[2 * t + 1];
    unsigned int packed = (unsigned short)f2bf(y0) |
                          ((unsigned int)(unsigned short)f2bf(y1) << 16);
    ((unsigned int*)out)[(long)s * (DMODEL / 2) + t] = packed;
}

// C[M,N] = A_bf16[M,512] @ B (+bias, epilogue).  K=512 fixed.
// BLAYOUT 0: B f32 [K,N].  1: B f32 [N,K].  2: Bb bf16 [N,K].
// EPI 0: Cf = acc + bias ; 1: Cf += acc + bias ; 2: Cb = bf16(gelu(acc+bias)) ; 3: Cf = acc
template<int BLAYOUT, int EPI>
__global__ __launch_bounds__(256) void gemm_kernel(
        const short* __restrict__ A, const float* __restrict__ B,
        const short* __restrict__ Bb, const float* __restrict__ bias,
        float* __restrict__ Cf, __hip_bfloat16* __restrict__ Cb, int N) {
    const int K = DMODEL;
    __shared__ __align__(16) short As[128 * 32];
    __shared__ __align__(16) short Bs[128 * 32];
    int t = threadIdx.x;
    int l = t & 63, wv = t >> 6;
    int wr = wv >> 1, wc = wv & 1;
    int m0 = blockIdx.y * 128, n0 = blockIdx.x * 128;
    int ln15 = l & 15, lh = l >> 4;

    float4v acc[4][4];
#pragma unroll
    for (int i = 0; i < 4; ++i)
#pragma unroll
        for (int j = 0; j < 4; ++j)
            acc[i][j] = (float4v){0.f, 0.f, 0.f, 0.f};

    int am = t >> 1;
    int acb = (t & 1) * 2;

    for (int k0 = 0; k0 < K; k0 += 32) {
        // ---- stage A (bf16, [128][32], XOR-swizzled) ----
        const short* Ag = A + (long)(m0 + am) * K + k0;
#pragma unroll
        for (int cc = 0; cc < 2; ++cc) {
            int c = acb + cc;
            float4v v = *(const float4v*)(Ag + c * 8);
            int cd = c ^ ((am >> 1) & 3);
            *(float4v*)(As + am * 32 + cd * 8) = v;
        }
        // ---- stage B ----
        if constexpr (BLAYOUT == 0) {
            int n = t & 127;
            int kgb = t >> 7;
            const float* Bg = B + (long)k0 * N + n0 + n;
#pragma unroll
            for (int g = 0; g < 4; ++g) {
                int kg = kgb + g * 2;
                short4v sv;
#pragma unroll
                for (int jj = 0; jj < 4; ++jj)
                    sv[jj] = f2bf(Bg[(long)(kg * 4 + jj) * N]);
                int ud = kg ^ (n & 6);
                *(short4v*)(Bs + n * 32 + ud * 4) = sv;
            }
        } else if constexpr (BLAYOUT == 1) {
            int n = t >> 1;
            int uh = (t & 1) * 4;
            const float* Bg = B + (long)(n0 + n) * K + k0;
#pragma unroll
            for (int uu = 0; uu < 4; ++uu) {
                int u = uh + uu;
                float4v v = *(const float4v*)(Bg + u * 4);
                short4v sv;
#pragma unroll
                for (int jj = 0; jj < 4; ++jj) sv[jj] = f2bf(v[jj]);
                int ud = u ^ (n & 6);
                *(short4v*)(Bs + n * 32 + ud * 4) = sv;
            }
        } else {
            int n = t >> 1;
            const short* Bg = Bb + (long)(n0 + n) * K + k0;
#pragma unroll
            for (int cc = 0; cc < 2; ++cc) {
                int c = (t & 1) * 2 + cc;
                float4v v = *(const float4v*)(Bg + c * 8);
                int cd = c ^ ((n >> 1) & 3);
                *(float4v*)(Bs + n * 32 + cd * 8) = v;
            }
        }
        __syncthreads();
        short8v af[4], bfr[4];
#pragma unroll
        for (int i = 0; i < 4; ++i) {
            int r = wr * 64 + i * 16 + ln15;
            HalfPair p{*(const short4v*)(As + r * 32 + ((lh ^ (r & 6)) << 2)),
                       *(const short4v*)(As + r * 32 + (((lh + 4) ^ (r & 6)) << 2))};
            af[i] = __builtin_bit_cast(short8v, p);
        }
#pragma unroll
        for (int j = 0; j < 4; ++j) {
            int r = wc * 64 + j * 16 + ln15;
            HalfPair p{*(const short4v*)(Bs + r * 32 + ((lh ^ (r & 6)) << 2)),
                       *(const short4v*)(Bs + r * 32 + (((lh + 4) ^ (r & 6)) << 2))};
            bfr[j] = __builtin_bit_cast(short8v, p);
        }
#pragma unroll
        for (int i = 0; i < 4; ++i)
#pragma unroll
            for (int j = 0; j < 4; ++j)
                acc[i][j] = mfma16x16x32(af[i], bfr[j], acc[i][j]);
        __syncthreads();
    }

    int colb = n0 + wc * 64 + ln15;
    int rowb = m0 + wr * 64 + (lh << 2);
#pragma unroll
    for (int i = 0; i < 4; ++i) {
#pragma unroll
        for (int j = 0; j < 4; ++j) {
            int col = colb + j * 16;
#pragma unroll
            for (int r = 0; r < 4; ++r) {
                int row = rowb + i * 16 + r;
                long idx = (long)row * N + col;
                float v = acc[i][j][r];
                if constexpr (EPI == 0) Cf[idx] = v + bias[col];
                else if constexpr (EPI == 1) Cf[idx] += v + bias[col];
                else if constexpr (EPI == 2)
                    Cb[idx] = __float2bfloat16(gelu_tanh(v + bias[col]));
                else Cf[idx] = v;
            }
        }
    }
}

// MFMA flash attention (swapped-operand). Block = 64 q-rows of one head, 4 waves.
// qkv [S][1536]: q at h*64, k at 512+h*64, v at 1024+h*64.
__global__ __launch_bounds__(256) void attn_mfma_kernel(
        const float* __restrict__ qkv, __hip_bfloat16* __restrict__ O) {
    __shared__ __align__(16) short Ks[64 * 64];  // [k][d] bf16, 8B unit u ^= (k&15)
    __shared__ __align__(16) short Vt[64 * 64];  // [d][k] bf16, 8B unit u ^= (d&15)
    int t = threadIdx.x, l = t & 63, w = t >> 6;
    int hh = blockIdx.y;
    int q0 = blockIdx.x * 64;
    int ln15 = l & 15, lh = l >> 4;

    // Q fragments (B-operand layout): lane holds Q[q=q0+16w+ln15][d=32dt+4lh+j (+16)]
    short8v qf[2];
    {
        const float* qrow = qkv + (long)(q0 + w * 16 + ln15) * 1536 + hh * 64;
#pragma unroll
        for (int dt = 0; dt < 2; ++dt) {
            float4v lo = *(const float4v*)(qrow + dt * 32 + lh * 4);
            float4v hi = *(const float4v*)(qrow + dt * 32 + 16 + lh * 4);
            short4v a, b;
#pragma unroll
            for (int j = 0; j < 4; ++j) { a[j] = f2bf(lo[j]); b[j] = f2bf(hi[j]); }
            HalfPair p{a, b};
            qf[dt] = __builtin_bit_cast(short8v, p);
        }
    }
    float m_run = -3e38f, l_run = 0.f;
    float4v oacc[4];  // O_swap[d = dt*16 + 4*lh + r][q = ln15]
#pragma unroll
    for (int dt = 0; dt < 4; ++dt) oacc[dt] = (float4v){0.f, 0.f, 0.f, 0.f};

    int nch = blockIdx.x + 1;
    for (int c = 0; c < nch; ++c) {
        int kk0 = c * 64;
        // ---- stage K[k][d] and Vt[d][k] (f32 -> bf16) ----
        {
            int row = t >> 2;                // k index 0..63
            int dc = (t & 3) * 16;           // d chunk
            const float* kp = qkv + (long)(kk0 + row) * 1536 + 512 + hh * 64 + dc;
#pragma unroll
            for (int i = 0; i < 4; ++i) {
                float4v kv = *(const float4v*)(kp + i * 4);
                short4v sv;
#pragma unroll
                for (int j = 0; j < 4; ++j) sv[j] = f2bf(kv[j]);
                int u = (dc >> 2) + i;
                *(short4v*)(Ks + row * 64 + (u ^ (row & 15)) * 4) = sv;
                float4v vv = *(const float4v*)(kp + 512 + i * 4);
#pragma unroll
                for (int j = 0; j < 4; ++j) {
                    int d = dc + i * 4 + j;
                    int ku = row >> 2;
                    Vt[d * 64 + ((ku ^ (d & 15)) << 2) + (row & 3)] = f2bf(vv[j]);
                }
            }
        }
        __syncthreads();
        // ---- swapped QK^T: s[kt] lane: S[k=kk0+kt*16+4lh+r][q=ln15] ----
        float4v s[4];
#pragma unroll
        for (int kt = 0; kt < 4; ++kt) {
            s[kt] = (float4v){0.f, 0.f, 0.f, 0.f};
#pragma unroll
            for (int dt = 0; dt < 2; ++dt) {
                int kr = kt * 16 + ln15;
                int u0 = dt * 8 + lh;
                HalfPair p{*(const short4v*)(Ks + kr * 64 + ((u0 ^ (kr & 15)) << 2)),
                           *(const short4v*)(Ks + kr * 64 + (((u0 + 4) ^ (kr & 15)) << 2))};
                s[kt] = mfma16x16x32(__builtin_bit_cast(short8v, p), qf[dt], s[kt]);
            }
        }
        // ---- mask + online softmax (lane-local q = ln15) ----
        int qg = q0 + w * 16 + ln15;
        float mx = m_run;
#pragma unroll
        for (int kt = 0; kt < 4; ++kt)
#pragma unroll
            for (int r = 0; r < 4; ++r) {
                int kg = kk0 + kt * 16 + lh * 4 + r;
                float sv = s[kt][r] * 0.125f;
                sv = (kg <= qg) ? sv : -3e38f;
                s[kt][r] = sv;
                mx = fmaxf(mx, sv);
            }
        mx = fmaxf(mx, __shfl_xor(mx, 16));
        mx = fmaxf(mx, __shfl_xor(mx, 32));
        float scale = __expf(m_run - mx);
        m_run = mx;
        float psum = 0.f;
#pragma unroll
        for (int kt = 0; kt < 4; ++kt)
#pragma unroll
            for (int r = 0; r < 4; ++r) {
                float p = __expf(s[kt][r] - mx);
                s[kt][r] = p;
                psum += p;
            }
        psum += __shfl_xor(psum, 16);
        psum += __shfl_xor(psum, 32);
        l_run = l_run * scale + psum;
        // ---- P -> bf16 A-fragments (pure in-lane) ----
        short8v pa[2];
#pragma unroll
        for (int t2 = 0; t2 < 2; ++t2) {
            short4v a, b;
#pragma unroll
            for (int r = 0; r < 4; ++r) {
                a[r] = f2bf(s[2 * t2][r]);
                b[r] = f2bf(s[2 * t2 + 1][r]);
            }
            HalfPair p{a, b};
            pa[t2] = __builtin_bit_cast(short8v, p);
        }
        // ---- rescale O, then swapped PV: mfma(Vt, P) -> O[d][q] ----
#pragma unroll
        for (int dt = 0; dt < 4; ++dt) {
            oacc[dt] *= scale;
#pragma unroll
            for (int t2 = 0; t2 < 2; ++t2) {
                int dr = dt * 16 + ln15;
                int u0 = t2 * 8 + lh;
                HalfPair p{*(const short4v*)(Vt + dr * 64 + ((u0 ^ (dr & 15)) << 2)),
                           *(const short4v*)(Vt + dr * 64 + (((u0 + 4) ^ (dr & 15)) << 2))};
                oacc[dt] = mfma16x16x32(__builtin_bit_cast(short8v, p), pa[t2], oacc[dt]);
            }
        }
        __syncthreads();
    }
    // ---- write O[q][d] = oacc / l_run ----
    float rl = 1.0f / l_run;
    int q = q0 + w * 16 + ln15;
    __hip_bfloat16* ob = O + (long)q * DMODEL + hh * 64;
#pragma unroll
    for (int dt = 0; dt < 4; ++dt) {
        short4v ov;
#pragma unroll
        for (int r = 0; r < 4; ++r) ov[r] = f2bf(oacc[dt][r] * rl);
        *(short4v*)((short*)ob + dt * 16 + lh * 4) = ov;
    }
}

extern "C" void kernel_launch(void* const* d_in, const int* in_sizes, int n_in,
                              void* d_out, int out_size, void* d_ws, size_t ws_size,
                              hipStream_t stream) {
    const int*   ids  = (const int*)d_in[0];
    const float* wte  = (const float*)d_in[1];
    const float* wpe  = (const float*)d_in[2];
    const float* qkvw = (const float*)d_in[3];
    const float* qkvb = (const float*)d_in[4];
    const float* pw   = (const float*)d_in[5];
    const float* pb   = (const float*)d_in[6];
    const float* l1w  = (const float*)d_in[7];
    const float* l1b  = (const float*)d_in[8];
    const float* l2w  = (const float*)d_in[9];
    const float* l2b  = (const float*)d_in[10];
    const float* fw   = (const float*)d_in[11];
    const float* fb   = (const float*)d_in[12];
    const float* mw   = (const float*)d_in[13];
    const float* mb   = (const float*)d_in[14];
    const float* lfw  = (const float*)d_in[15];
    const float* lfb  = (const float*)d_in[16];
    const float* hw   = (const float*)d_in[17];

    // ws layout: x f32 | qkv f32 | h bf16 | o bf16 | g bf16 | [hw_bf16 if room]
    float* x   = (float*)d_ws;
    float* qkv = x + (long)S_LEN * DMODEL;
    short* h   = (short*)(qkv + (long)S_LEN * 3 * DMODEL);
    short* o   = h + (long)S_LEN * DMODEL;
    short* g   = o + (long)S_LEN * DMODEL;
    short* hwb = g + (long)S_LEN * DMODEL;
    const long base_bytes = (long)((char*)hwb - (char*)d_ws);
    const long hw_elems = 32000L * DMODEL;
    bool use_bf = (long)ws_size >= base_bytes + hw_elems * 2;
    float* out = (float*)d_out;

    embed_kernel<<<S_LEN, 128, 0, stream>>>(ids, wte, wpe, x);
    if (use_bf)
        f2bf_kernel<<<(int)(hw_elems / (256 * 8)), 256, 0, stream>>>(hw, hwb, hw_elems);
    for (int lyr = 0; lyr < NLAYER; ++lyr) {
        ln_kernel<<<S_LEN, 256, 0, stream>>>(x, l1w + lyr * DMODEL, l1b + lyr * DMODEL,
                                             (__hip_bfloat16*)h);
        gemm_kernel<0, 0><<<dim3(12, 16), 256, 0, stream>>>(
            h, qkvw + (long)lyr * DMODEL * 1536, nullptr, qkvb + lyr * 1536,
            qkv, nullptr, 1536);
        attn_mfma_kernel<<<dim3(32, 8), 256, 0, stream>>>(qkv, (__hip_bfloat16*)o);
        gemm_kernel<0, 1><<<dim3(4, 16), 256, 0, stream>>>(
            o, pw + (long)lyr * DMODEL * DMODEL, nullptr, pb + lyr * DMODEL,
            x, nullptr, DMODEL);
        ln_kernel<<<S_LEN, 256, 0, stream>>>(x, l2w + lyr * DMODEL, l2b + lyr * DMODEL,
                                             (__hip_bfloat16*)h);
        gemm_kernel<0, 2><<<dim3(4, 16), 256, 0, stream>>>(
            h, fw + (long)lyr * DMODEL * DMODEL, nullptr, fb + lyr * DMODEL,
            nullptr, (__hip_bfloat16*)g, DMODEL);
        gemm_kernel<0, 1><<<dim3(4, 16), 256, 0, stream>>>(
            g, mw + (long)lyr * DMODEL * DMODEL, nullptr, mb + lyr * DMODEL,
            x, nullptr, DMODEL);
    }
    ln_kernel<<<S_LEN, 256, 0, stream>>>(x, lfw, lfb, (__hip_bfloat16*)h);
    if (use_bf)
        gemm_kernel<2, 3><<<dim3(250, 16), 256, 0, stream>>>(
            h, nullptr, hwb, nullptr, out, nullptr, 32000);
    else
        gemm_kernel<1, 3><<<dim3(250, 16), 256, 0, stream>>>(
            h, hw, nullptr, nullptr, out, nullptr, 32000);
}